// Round 1
// baseline (27.851 us; speedup 1.0000x reference)
//
#include <hip/hip_runtime.h>

// Sizes fixed by the reference: B=512, H=1024, D=5, 32 multivector comps.
#define NB 512
#define NH 1024
#define ND 5
// 1 - (1-dt)^N_FREE = 1 - 0.9^10
#define SCALE 0.6513215599f

// Cayley sign for Cl(4,1), metric diag(1,1,1,1,-1):
// e_a * e_b = sign(a,b) * e_{a^b}
__device__ __forceinline__ float cl_sign(int a, int b) {
    int cnt = 0;
    int aa = a >> 1;
    while (aa) { cnt += __popc(aa & b); aa >>= 1; }
    float s = (cnt & 1) ? -1.0f : 1.0f;
    if ((a & b) & 16) s = -s;   // e5*e5 = -1 (bit 4)
    return s;
}

// G[d*1024 + s*32 + q] = sum_h W_in[h,d,s] * W_out[h,q]
// grid = 160 blocks (one per (d,s)), block = 256 (= 32 q x 8 h-chunks)
__global__ void k_G(const float* __restrict__ Win, const float* __restrict__ Wout,
                    float* __restrict__ G) {
    const int ds = blockIdx.x;          // d*32 + s
    const int d = ds >> 5, s = ds & 31;
    const int t = threadIdx.x;
    const int q = t & 31;
    const int chunk = t >> 5;           // 0..7
    float acc = 0.0f;
    const int h0 = chunk * (NH / 8);
    for (int h = h0; h < h0 + NH / 8; ++h) {
        acc += Win[h * (ND * 32) + d * 32 + s] * Wout[h * 32 + q];
    }
    __shared__ float red[256];
    red[t] = acc;
    __syncthreads();
    if (t < 32) {
        float sum = 0.0f;
        #pragma unroll
        for (int c = 0; c < 8; ++c) sum += red[c * 32 + t];
        G[d * 1024 + s * 32 + t] = sum;
    }
}

// K[d*1024 + r*32 + k] = SCALE * sum_s sign(r,s) * sign(r^s, r^s^k) * G[d, s, r^s^k]
// grid = 5 blocks (one per d), block = 1024 (= 32 r x 32 k)
__global__ void k_K(const float* __restrict__ G, float* __restrict__ K) {
    const int d = blockIdx.x;
    const int t = threadIdx.x;          // r*32 + k
    __shared__ float gs[1024];
    __shared__ float sg[1024];
    gs[t] = G[d * 1024 + t];
    sg[t] = cl_sign(t >> 5, t & 31);
    __syncthreads();
    const int r = t >> 5, k = t & 31;
    float acc = 0.0f;
    #pragma unroll
    for (int s = 0; s < 32; ++s) {
        const int p = r ^ s;
        const int q = p ^ k;
        acc += sg[r * 32 + s] * sg[p * 32 + q] * gs[s * 32 + q];
    }
    K[d * 1024 + t] = SCALE * acc;
}

// out[b*32 + k] = sum_{d,r} x[b,d,r] * K[d,r,k]
// grid = 64 blocks, block = 256 (= 8 b x 32 k)
__global__ void k_pred(const float* __restrict__ x, const float* __restrict__ K,
                       float* __restrict__ out) {
    __shared__ float ks[ND * 1024];
    const int t = threadIdx.x;
    for (int i = t; i < ND * 1024; i += 256) ks[i] = K[i];
    __syncthreads();
    const int b = blockIdx.x * 8 + (t >> 5);
    const int k = t & 31;
    float acc = 0.0f;
    #pragma unroll
    for (int d = 0; d < ND; ++d) {
        #pragma unroll
        for (int r = 0; r < 32; ++r) {
            acc += x[b * (ND * 32) + d * 32 + r] * ks[d * 1024 + r * 32 + k];
        }
    }
    out[b * 32 + k] = acc;
}

extern "C" void kernel_launch(void* const* d_in, const int* in_sizes, int n_in,
                              void* d_out, int out_size, void* d_ws, size_t ws_size,
                              hipStream_t stream) {
    const float* x_mv  = (const float*)d_in[0];   // (512, 5, 32)
    const float* W_in  = (const float*)d_in[1];   // (1024, 5, 32)
    const float* W_out = (const float*)d_in[2];   // (1, 1024, 32)
    float* out = (float*)d_out;                   // (512, 1, 32)

    float* G = (float*)d_ws;                      // 5120 floats
    float* K = G + ND * 1024;                     // 5120 floats

    k_G<<<ND * 32, 256, 0, stream>>>(W_in, W_out, G);
    k_K<<<ND, 1024, 0, stream>>>(G, K);
    k_pred<<<NB / 8, 256, 0, stream>>>(x_mv, K, out);
}

// Round 2
// 17.957 us; speedup vs baseline: 1.5510x; 1.5510x over previous
//
#include <hip/hip_runtime.h>

// Sizes fixed by the reference: B=512, H=1024, D=5, 32 multivector comps.
#define NB 512
#define NH 1024
#define ND 5
#define NCH 32              // h-chunks for the G reduction
#define CH (NH / NCH)       // 32 h per chunk
// 1 - (1-dt)^N_FREE = 1 - 0.9^10
#define SCALE 0.6513215599f

// Cayley sign for Cl(4,1), metric diag(1,1,1,1,-1): e_a*e_b = sign(a,b)*e_{a^b}
__device__ __forceinline__ float cl_sign(int a, int b) {
    int cnt = 0;
    int aa = a >> 1;
    while (aa) { cnt += __popc(aa & b); aa >>= 1; }
    float s = (cnt & 1) ? -1.0f : 1.0f;
    if ((a & b) & 16) s = -s;   // e5*e5 = -1 (bit 4)
    return s;
}

// Partial G over an h-chunk: Gp[(hc*ND + d)*1024 + s*32 + q] =
//   sum_{h in chunk} W_in[h,d,s] * W_out[h,q]
// grid = ND*NCH blocks, block = 256 threads (each owns a 2x2 (s,q) tile).
__global__ void k_Gpart(const float* __restrict__ Win, const float* __restrict__ Wout,
                        float* __restrict__ Gp) {
    const int d  = blockIdx.x >> 5;        // 0..4
    const int hc = blockIdx.x & 31;        // 0..31
    const int h0 = hc * CH;
    __shared__ float as[CH][32];
    __shared__ float bs[CH][32];
    const int t = threadIdx.x;
    for (int i = t; i < CH * 32; i += 256) {
        const int h = h0 + (i >> 5);
        const int c = i & 31;
        as[i >> 5][c] = Win[h * (ND * 32) + d * 32 + c];
        bs[i >> 5][c] = Wout[h * 32 + c];
    }
    __syncthreads();
    const int s0 = (t >> 4) << 1;          // 0..30 even
    const int q0 = (t & 15) << 1;          // 0..30 even
    float a00 = 0.f, a01 = 0.f, a10 = 0.f, a11 = 0.f;
    #pragma unroll
    for (int h = 0; h < CH; ++h) {
        const float2 av = *(const float2*)&as[h][s0];
        const float2 bv = *(const float2*)&bs[h][q0];
        a00 += av.x * bv.x; a01 += av.x * bv.y;
        a10 += av.y * bv.x; a11 += av.y * bv.y;
    }
    float* o = Gp + (hc * ND + d) * 1024;
    o[s0 * 32 + q0]           = a00;
    o[s0 * 32 + q0 + 1]       = a01;
    o[(s0 + 1) * 32 + q0]     = a10;
    o[(s0 + 1) * 32 + q0 + 1] = a11;
}

// K[d*1024 + r*32 + k] = SCALE * sum_s sign(r,s)*sign(r^s, r^s^k)*G[d, s, r^s^k]
// grid = ND blocks, block = 1024 (= 32 r x 32 k)
__global__ void k_K(const float* __restrict__ Gp, float* __restrict__ K) {
    const int d = blockIdx.x;
    const int t = threadIdx.x;             // r*32 + k
    __shared__ float gs[1024];
    __shared__ float sg[1024];
    float sum = 0.0f;
    #pragma unroll
    for (int hc = 0; hc < NCH; ++hc)
        sum += Gp[(hc * ND + d) * 1024 + t];
    gs[t] = sum;
    sg[t] = cl_sign(t >> 5, t & 31);
    __syncthreads();
    const int r = t >> 5, k = t & 31;
    float acc = 0.0f;
    #pragma unroll
    for (int s = 0; s < 32; ++s) {
        const int p = r ^ s;
        const int q = p ^ k;
        acc += sg[r * 32 + s] * sg[p * 32 + q] * gs[s * 32 + q];
    }
    K[d * 1024 + t] = SCALE * acc;
}

// out[b*32 + k] = sum_{d,r} x[b,d,r] * K[d,r,k]
// grid = NB/8 blocks, block = 256 (= 8 b x 32 k)
__global__ void k_pred(const float* __restrict__ x, const float* __restrict__ K,
                       float* __restrict__ out) {
    __shared__ float ks[ND * 1024];
    __shared__ float xs[8 * ND * 32];      // 1280 floats
    const int t = threadIdx.x;
    const int b0 = blockIdx.x * 8;
    for (int i = t; i < ND * 1024; i += 256) ks[i] = K[i];
    for (int i = t; i < 8 * ND * 32; i += 256) xs[i] = x[b0 * (ND * 32) + i];
    __syncthreads();
    const int bl = t >> 5, k = t & 31;
    float acc = 0.0f;
    #pragma unroll
    for (int d = 0; d < ND; ++d) {
        #pragma unroll
        for (int r4 = 0; r4 < 8; ++r4) {
            const float4 xv = *(const float4*)&xs[bl * 160 + d * 32 + r4 * 4];
            acc += xv.x * ks[d * 1024 + (r4 * 4 + 0) * 32 + k];
            acc += xv.y * ks[d * 1024 + (r4 * 4 + 1) * 32 + k];
            acc += xv.z * ks[d * 1024 + (r4 * 4 + 2) * 32 + k];
            acc += xv.w * ks[d * 1024 + (r4 * 4 + 3) * 32 + k];
        }
    }
    out[(b0 + bl) * 32 + k] = acc;
}

extern "C" void kernel_launch(void* const* d_in, const int* in_sizes, int n_in,
                              void* d_out, int out_size, void* d_ws, size_t ws_size,
                              hipStream_t stream) {
    const float* x_mv  = (const float*)d_in[0];   // (512, 5, 32)
    const float* W_in  = (const float*)d_in[1];   // (1024, 5, 32)
    const float* W_out = (const float*)d_in[2];   // (1, 1024, 32)
    float* out = (float*)d_out;                   // (512, 1, 32)

    float* Gp = (float*)d_ws;                     // NCH*ND*1024 floats (640 KB)
    float* K  = Gp + NCH * ND * 1024;             // 5120 floats

    k_Gpart<<<ND * NCH, 256, 0, stream>>>(W_in, W_out, Gp);
    k_K<<<ND, 1024, 0, stream>>>(Gp, K);
    k_pred<<<NB / 8, 256, 0, stream>>>(x_mv, K, out);
}